// Round 3
// baseline (889.667 us; speedup 1.0000x reference)
//
#include <hip/hip_runtime.h>

#define M_ 16
#define H_ 32
#define D_ 128
#define P_ 8192
#define N_ 4096
#define PM_ 8208   // P + M

// workspace layout (float offsets) — no region needs pre-zeroing
#define WS_Q    0          // [32][16][128] q
#define WS_K    65536      // [32][16][128] new k
#define WS_V    131072     // [32][16][128] new v
#define WS_S1   196608     // [512] final denominators (exp(c))
#define WS_S2   197120     // [512] final denominators (perturbed)
#define WS_IS2  197632     // [512] 1/s2
#define WS_XQ   198144     // x_norm as float4 [1024][16] (n-quad major, m minor)
#define WS_E2   263680     // e2t [32][8208][16]  (h, p, m) — transposed for coalescing
#define WS_PP   263680     // proj partials [16][16][12288] — ALIASES E2 (consumed before attn)
#define WS_PO   4466176    // attn O partials [32][32][16][128] (h, block, m, d)
#define WS_SP1  6563328    // [32*32*16] s1 partials per (h, block, m)
#define WS_SP2  6579712    // [32*32*16]
// total = 6,596,096 floats = 26.4 MB

// ---------------- Kernel A: RMS norm, write transposed-quad layout ----------------
__global__ __launch_bounds__(256) void rmsnorm_kernel(const float* __restrict__ X,
                                                      float* __restrict__ ws) {
  int m = blockIdx.x, t = threadIdx.x;
  __shared__ float red[256];
  const float4* X4 = (const float4*)(X + (size_t)m * N_);
  float s = 0.f;
  #pragma unroll
  for (int q = 0; q < 4; q++) {
    float4 v = X4[t + q * 256];
    s += v.x * v.x + v.y * v.y + v.z * v.z + v.w * v.w;
  }
  red[t] = s;
  __syncthreads();
  for (int off = 128; off > 0; off >>= 1) {
    if (t < off) red[t] += red[t + off];
    __syncthreads();
  }
  float scale = rsqrtf(red[0] * (1.0f / N_));
  float4* xq = (float4*)(ws + WS_XQ);
  #pragma unroll
  for (int q = 0; q < 4; q++) {
    int nq = t + q * 256;
    float4 v = X4[nq];
    v.x *= scale; v.y *= scale; v.z *= scale; v.w *= scale;
    xq[nq * 16 + m] = v;  // xq[n/4][m]
  }
}

// ---------------- Kernel B: QKV projection (k-split x16, reg-dbuf pipeline) ----------------
__global__ __launch_bounds__(256) void proj_kernel(const float* __restrict__ Wq,
                                                   const float* __restrict__ Wk,
                                                   const float* __restrict__ Wv,
                                                   float* __restrict__ ws) {
  __shared__ float tile[4 * 64 * 32];  // 32 KB, one 8KB tile per wave
  int widx = threadIdx.x >> 6, lane = threadIdx.x & 63;
  int w = blockIdx.x * 4 + widx;   // 0..3071
  int kc = w / 192;                // k-chunk 0..15
  int jt = w % 192;                // j-tile over 12288 combined cols
  int jj0 = jt * 64;
  int sel = jj0 >> 12;             // 0=q 1=k 2=v
  int j0 = jj0 & 4095;
  const float* Wm = (sel == 0) ? Wq : ((sel == 1) ? Wk : Wv);
  const float4* xq = (const float4*)(ws + WS_XQ);
  float* tl = tile + widx * 2048;

  float acc[16];
  #pragma unroll
  for (int m = 0; m < 16; m++) acc[m] = 0.f;

  int n0 = kc * 256;
  int r_ = lane >> 3, c_ = lane & 7;

  float4 gA[8], gB[8];
  auto loadT = [&](float4* dst, int ti) {
    int nb = n0 + ti * 32;
    #pragma unroll
    for (int i = 0; i < 8; i++) {
      int r = i * 8 + r_;
      dst[i] = *(const float4*)(Wm + (size_t)(j0 + r) * N_ + nb + c_ * 4);
    }
  };
  auto stage = [&](const float4* src) {
    #pragma unroll
    for (int i = 0; i < 8; i++) {
      int r = i * 8 + r_;
      *(float4*)&tl[r * 32 + ((c_ ^ (r & 7)) << 2)] = src[i];
    }
  };
  auto compute = [&](int ti) {
    int nb = n0 + ti * 32;
    #pragma unroll
    for (int k = 0; k < 8; k++) {
      float4 w4 = *(const float4*)&tl[lane * 32 + ((k ^ (lane & 7)) << 2)];
      int qbase = ((nb >> 2) + k) * 16;
      #pragma unroll
      for (int m = 0; m < 16; m++) {
        float4 xm = xq[qbase + m];  // wave-uniform -> scalar/broadcast
        acc[m] += xm.x * w4.x + xm.y * w4.y + xm.z * w4.z + xm.w * w4.w;
      }
    }
  };

  loadT(gA, 0);
  #pragma unroll
  for (int ti = 0; ti < 8; ti += 2) {
    if (ti + 1 < 8) loadT(gB, ti + 1);
    stage(gA);
    compute(ti);
    if (ti + 2 < 8) loadT(gA, ti + 2);
    if (ti + 1 < 8) { stage(gB); compute(ti + 1); }
  }

  // partial store: PP[kc][m][jj0+lane], coalesced 256B per m
  float* pp = ws + WS_PP + (size_t)kc * 16 * 12288 + jj0 + lane;
  #pragma unroll
  for (int m = 0; m < 16; m++) pp[(size_t)m * 12288] = acc[m];
}

// ---------------- Kernel B2: reduce proj partials over kc ----------------
__global__ __launch_bounds__(256) void proj_reduce_kernel(float* __restrict__ ws) {
  int tid = blockIdx.x * 256 + threadIdx.x;  // 0..196607
  int m = tid / 12288;
  int j = tid - m * 12288;
  float acc = 0.f;
  #pragma unroll
  for (int kc = 0; kc < 16; kc++)
    acc += ws[WS_PP + ((size_t)(kc * 16 + m)) * 12288 + j];
  int sel = j >> 12, jj = j & 4095;
  int h = jj >> 7, d = jj & 127;
  ws[WS_Q + sel * 65536 + (h * 16 + m) * 128 + d] = acc;
}

// ---------------- Kernel C1: attention main pass ----------------
// lane = (m8 = lane&7, sl = lane>>3). Each lane owns m in {m8, m8+8}, d-slice
// sl*16..sl*16+15. Per 4-row group: K loads (128B distinct/instr, 8-way dup
// TA-merged) -> 32 FMA/row -> shfl_xor(8,16,32) butterfly (all lanes get all
// 8 row-dots) -> exps -> coalesced transposed e2t store -> V accumulate.
__global__ __launch_bounds__(256) void attn_kernel(const float* __restrict__ cacheK,
                                                   const float* __restrict__ cacheV,
                                                   const float* __restrict__ noise,
                                                   const float* __restrict__ taup,
                                                   float* __restrict__ ws) {
  __shared__ float red[4 * 2048];      // 32KB, rotation-swizzled [wave][lane][32]
  __shared__ float sred[2][4][16];
  int h = blockIdx.x >> 5, b = blockIdx.x & 31;
  int widx = threadIdx.x >> 6, lane = threadIdx.x & 63;
  int m8 = lane & 7, sl = lane >> 3;
  int rsel = lane >> 4;        // row slot this lane handles for e2/s-sums
  int msel = lane & 15;        // m this lane handles for e2/s-sums
  int tsel = (lane >> 3) & 1;  // which t-half holds msel: m8 + 8*tsel == msel
  float inv_tau = 1.0f / taup[0];

  float qv[2][16];
  #pragma unroll
  for (int t = 0; t < 2; t++) {
    const float4* qp = (const float4*)(ws + WS_Q + ((size_t)(h * 16) + m8 + 8 * t) * 128 + sl * 16);
    #pragma unroll
    for (int jq = 0; jq < 4; jq++) {
      float4 v = qp[jq];
      qv[t][jq * 4] = v.x; qv[t][jq * 4 + 1] = v.y;
      qv[t][jq * 4 + 2] = v.z; qv[t][jq * 4 + 3] = v.w;
    }
  }
  float oacc[2][16];
  #pragma unroll
  for (int t = 0; t < 2; t++)
    #pragma unroll
    for (int j = 0; j < 16; j++) oacc[t][j] = 0.f;
  float s1 = 0.f, s2 = 0.f;

  const float* nbase = noise + ((size_t)h * 16 + msel) * PM_;
  float* e2base = ws + WS_E2 + (size_t)h * PM_ * 16 + msel;
  const float* kc_base = cacheK + (size_t)h * P_ * D_;
  const float* vc_base = cacheV + (size_t)h * P_ * D_;
  const float* kn_base = ws + WS_K + (size_t)h * 16 * 128;
  const float* vn_base = ws + WS_V + (size_t)h * 16 * 128;

  int g0 = b * 64;
  int gN = (b == 31) ? 68 : 64;
  for (int gl = widx; gl < gN; gl += 4) {
    int p0 = (g0 + gl) * 4;
    const float *kb, *vb;
    if (p0 < P_) { kb = kc_base + (size_t)p0 * D_; vb = vc_base + (size_t)p0 * D_; }
    else { kb = kn_base + (size_t)(p0 - P_) * D_; vb = vn_base + (size_t)(p0 - P_) * D_; }

    // QK^T partials
    float pr[4][2];
    #pragma unroll
    for (int r = 0; r < 4; r++) {
      float4 kq[4];
      const float4* krp = (const float4*)(kb + r * D_ + sl * 16);
      kq[0] = krp[0]; kq[1] = krp[1]; kq[2] = krp[2]; kq[3] = krp[3];
      const float* kk = (const float*)kq;
      float t0 = 0.f, t1 = 0.f;
      #pragma unroll
      for (int j = 0; j < 16; j++) { t0 += kk[j] * qv[0][j]; t1 += kk[j] * qv[1][j]; }
      pr[r][0] = t0; pr[r][1] = t1;
    }
    // butterfly reduce over sl (bits 3,4,5) -> all lanes have all 8 dots
    float cc[4][2];
    #pragma unroll
    for (int r = 0; r < 4; r++)
      #pragma unroll
      for (int t = 0; t < 2; t++) {
        float v = pr[r][t];
        v += __shfl_xor(v, 8, 64);
        v += __shfl_xor(v, 16, 64);
        v += __shfl_xor(v, 32, 64);
        cc[r][t] = v;
      }

    // perturbed exp: one (row, m) slot per lane; coalesced transposed store
    float nz = nbase[p0 + rsel];
    float myc = cc[rsel][tsel];
    float e2 = __expf((myc + nz) * inv_tau);
    e2base[(size_t)(p0 + rsel) * 16] = e2;
    s2 += e2;

    float e1[4][2];
    #pragma unroll
    for (int r = 0; r < 4; r++) {
      e1[r][0] = __expf(cc[r][0]);
      e1[r][1] = __expf(cc[r][1]);
    }
    s1 += e1[rsel][tsel];

    // PV accumulate
    #pragma unroll
    for (int r = 0; r < 4; r++) {
      float4 vq[4];
      const float4* vrp = (const float4*)(vb + r * D_ + sl * 16);
      vq[0] = vrp[0]; vq[1] = vrp[1]; vq[2] = vrp[2]; vq[3] = vrp[3];
      const float* vv = (const float*)vq;
      float ea = e1[r][0], eb = e1[r][1];
      #pragma unroll
      for (int j = 0; j < 16; j++) {
        oacc[0][j] += ea * vv[j];
        oacc[1][j] += eb * vv[j];
      }
    }
  }

  // ---- s1/s2: reduce over row-slots (lanes ±16, ±32 share msel) ----
  s1 += __shfl_xor(s1, 16, 64); s1 += __shfl_xor(s1, 32, 64);
  s2 += __shfl_xor(s2, 16, 64); s2 += __shfl_xor(s2, 32, 64);
  if (lane < 16) { sred[0][widx][lane] = s1; sred[1][widx][lane] = s2; }

  // ---- block-level O reduce (rotation swizzle: 2 lanes/bank max) ----
  float* rw = red + widx * 2048 + lane * 32;
  #pragma unroll
  for (int t = 0; t < 2; t++)
    #pragma unroll
    for (int j = 0; j < 16; j++) {
      int i = t * 16 + j;
      rw[(i + lane) & 31] = oacc[t][j];
    }
  __syncthreads();

  float* po = ws + WS_PO + (size_t)(h * 32 + b) * 2048;
  for (int e = threadIdx.x; e < 2048; e += 256) {
    int ln = e >> 5, i = e & 31;
    int phys = (ln << 5) + ((i + ln) & 31);
    float v = red[phys] + red[phys + 2048] + red[phys + 4096] + red[phys + 6144];
    int mo = (ln & 7) + 8 * (i >> 4);
    int d = (ln >> 3) * 16 + (i & 15);
    po[mo * 128 + d] = v;
  }
  if (threadIdx.x < 16) {
    int mm = threadIdx.x;
    float a  = sred[0][0][mm] + sred[0][1][mm] + sred[0][2][mm] + sred[0][3][mm];
    float c2 = sred[1][0][mm] + sred[1][1][mm] + sred[1][2][mm] + sred[1][3][mm];
    ws[WS_SP1 + (size_t)(h * 32 + b) * 16 + mm] = a;
    ws[WS_SP2 + (size_t)(h * 32 + b) * 16 + mm] = c2;
  }
}

// ---------------- Kernel S: final s1/s2 sums + 1/s2 ----------------
__global__ __launch_bounds__(256) void sums_kernel(float* __restrict__ ws) {
  int tid = blockIdx.x * 256 + threadIdx.x;
  if (tid >= 512) return;
  int h = tid >> 4, m = tid & 15;
  float a = 0.f, c2 = 0.f;
  #pragma unroll
  for (int b = 0; b < 32; b++) {
    a  += ws[WS_SP1 + (size_t)(h * 32 + b) * 16 + m];
    c2 += ws[WS_SP2 + (size_t)(h * 32 + b) * 16 + m];
  }
  ws[WS_S1 + tid] = a;
  ws[WS_S2 + tid] = c2;
  ws[WS_IS2 + tid] = 1.0f / c2;
}

// ---------------- Kernel D: o2 epilogue ----------------
__global__ __launch_bounds__(256) void epilogue_kernel(const float* __restrict__ ws,
                                                       float* __restrict__ out) {
  int tid = blockIdx.x * 256 + threadIdx.x;  // 0..65535
  int mm = tid >> 12, j = tid & 4095;
  int h = j >> 7, d = j & 127;
  float acc = 0.f;
  #pragma unroll
  for (int b = 0; b < 32; b++)
    acc += ws[WS_PO + (size_t)(h * 32 + b) * 2048 + mm * 128 + d];
  out[tid] = acc / ws[WS_S1 + h * 16 + mm];
}

// ---------------- Kernel C2: c_out (contiguous e2t reads) ----------------
__global__ __launch_bounds__(256) void cout_kernel(const float* __restrict__ ws,
                                                   float* __restrict__ out) {
  int tid = blockIdx.x * 256 + threadIdx.x;
  if (tid >= H_ * PM_) return;
  int h = tid / PM_, p = tid - h * PM_;
  const float4* e2p = (const float4*)(ws + WS_E2 + ((size_t)h * PM_ + p) * 16);
  const float* is2 = ws + WS_IS2 + h * 16;
  float acc = 0.f;
  #pragma unroll
  for (int q = 0; q < 4; q++) {
    float4 v = e2p[q];
    acc += v.x * is2[q * 4] + v.y * is2[q * 4 + 1] + v.z * is2[q * 4 + 2] + v.w * is2[q * 4 + 3];
  }
  out[65536 + tid] = acc;
}

extern "C" void kernel_launch(void* const* d_in, const int* in_sizes, int n_in,
                              void* d_out, int out_size, void* d_ws, size_t ws_size,
                              hipStream_t stream) {
  const float* X     = (const float*)d_in[0];
  const float* Wq    = (const float*)d_in[1];
  const float* Wk    = (const float*)d_in[2];
  const float* Wv    = (const float*)d_in[3];
  const float* cK    = (const float*)d_in[4];
  const float* cV    = (const float*)d_in[5];
  const float* tau   = (const float*)d_in[6];
  const float* noise = (const float*)d_in[7];
  float* out = (float*)d_out;
  float* ws  = (float*)d_ws;

  rmsnorm_kernel<<<16, 256, 0, stream>>>(X, ws);
  proj_kernel<<<768, 256, 0, stream>>>(Wq, Wk, Wv, ws);
  proj_reduce_kernel<<<768, 256, 0, stream>>>(ws);
  attn_kernel<<<1024, 256, 0, stream>>>(cK, cV, noise, tau, ws);
  sums_kernel<<<2, 256, 0, stream>>>(ws);
  epilogue_kernel<<<256, 256, 0, stream>>>(ws, out);
  cout_kernel<<<1026, 256, 0, stream>>>(ws, out);
}

// Round 4
// 315.150 us; speedup vs baseline: 2.8230x; 2.8230x over previous
//
#include <hip/hip_runtime.h>

#define M_ 16
#define H_ 32
#define D_ 128
#define P_ 8192
#define N_ 4096
#define PM_ 8208   // P + M

// workspace layout (float offsets) — no region needs pre-zeroing
#define WS_Q    0          // [32][16][128] q
#define WS_K    65536      // [32][16][128] new k
#define WS_V    131072     // [32][16][128] new v
#define WS_S1   196608     // [512] final denominators (exp(c))
#define WS_S2   197120     // [512] final denominators (perturbed)
#define WS_IS2  197632     // [512] 1/s2
#define WS_XQ   198144     // x_norm as float4 [1024][16] (n-quad major, m minor)
#define WS_E2   263680     // e2t [32][8208][16]  (h, p, m) — transposed for coalescing
#define WS_PP   263680     // proj partials [16][16][12288] — ALIASES E2 (consumed before attn)
#define WS_PO   4466176    // attn O partials [32][32][16][128] (h, block, m, d)
#define WS_SP1  6563328    // [32*32*16] s1 partials per (h, block, m)
#define WS_SP2  6579712    // [32*32*16]
// total = 6,596,096 floats = 26.4 MB

typedef __attribute__((address_space(1))) const void gvoid_t;
typedef __attribute__((address_space(3))) void lvoid_t;

// ---------------- Kernel A: RMS norm, write transposed-quad layout ----------------
__global__ __launch_bounds__(256) void rmsnorm_kernel(const float* __restrict__ X,
                                                      float* __restrict__ ws) {
  int m = blockIdx.x, t = threadIdx.x;
  __shared__ float red[256];
  const float4* X4 = (const float4*)(X + (size_t)m * N_);
  float s = 0.f;
  #pragma unroll
  for (int q = 0; q < 4; q++) {
    float4 v = X4[t + q * 256];
    s += v.x * v.x + v.y * v.y + v.z * v.z + v.w * v.w;
  }
  red[t] = s;
  __syncthreads();
  for (int off = 128; off > 0; off >>= 1) {
    if (t < off) red[t] += red[t + off];
    __syncthreads();
  }
  float scale = rsqrtf(red[0] * (1.0f / N_));
  float4* xq = (float4*)(ws + WS_XQ);
  #pragma unroll
  for (int q = 0; q < 4; q++) {
    int nq = t + q * 256;
    float4 v = X4[nq];
    v.x *= scale; v.y *= scale; v.z *= scale; v.w *= scale;
    xq[nq * 16 + m] = v;  // xq[n/4][m]
  }
}

// ---------------- Kernel B: QKV projection ----------------
// kc is BLOCK-uniform (scalar): x loads provably uniform -> s_load path.
// W staged via global_load_lds (16B) with source-swizzled global addresses,
// linear LDS dest, XOR-swizzled ds_read_b128 (involution: cq = c8 ^ g8).
// Per-wave private 8KB tile, no barriers. j-per-lane accumulation, acc[16].
__global__ __launch_bounds__(256, 4) void proj_kernel(const float* __restrict__ Wq,
                                                      const float* __restrict__ Wk,
                                                      const float* __restrict__ Wv,
                                                      const float* __restrict__ xr,
                                                      float* __restrict__ ws) {
  __shared__ float tile[4 * 2048];  // 8KB per wave
  int widx = threadIdx.x >> 6, lane = threadIdx.x & 63;
  int kc = blockIdx.x / 48;                 // 0..15, scalar (blockIdx only)
  int jt = (blockIdx.x % 48) * 4 + widx;    // 0..191
  int jj0 = jt * 64;
  int sel = jj0 >> 12;                      // 0=q 1=k 2=v
  int j0 = jj0 & 4095;
  const float* Wm = (sel == 0) ? Wq : ((sel == 1) ? Wk : Wv);
  int n0 = kc * 256;

  float* tl = tile + widx * 2048;
  int g8 = lane >> 3;        // row-subgroup 0..7
  int c8 = lane & 7;         // col-slot 0..7
  int cq = c8 ^ g8;          // source-swizzled col-quad (involution)

  // per-instr global source pointers: row = i*8+g8, col-quad = cq
  const float* gsrc[8];
  #pragma unroll
  for (int i = 0; i < 8; i++)
    gsrc[i] = Wm + (size_t)(j0 + i * 8 + g8) * N_ + n0 + cq * 4;

  const float4* tl4 = (const float4*)tl;
  int rbase = lane * 8;      // float4-index base of this lane's j-row
  int swz = lane & 7;

  const float4* xr4 = (const float4*)xr;
  float acc[16];
  #pragma unroll
  for (int m = 0; m < 16; m++) acc[m] = 0.f;

  for (int ti = 0; ti < 8; ti++) {
    // stage 64 rows x 32 floats: 8 x global_load_lds dwordx4 (linear LDS dest)
    #pragma unroll
    for (int i = 0; i < 8; i++)
      __builtin_amdgcn_global_load_lds((gvoid_t*)(gsrc[i] + ti * 32),
                                       (lvoid_t*)(tl + i * 256), 16, 0, 0);
    asm volatile("s_waitcnt vmcnt(0)" ::: "memory");
    __builtin_amdgcn_sched_barrier(0);

    int nqb = (n0 >> 2) + ti * 8;
    #pragma unroll
    for (int k = 0; k < 8; k++) {
      float4 w4 = tl4[rbase + (k ^ swz)];   // swizzled read: banks spread
      int qbase = (nqb + k) * 16;
      #pragma unroll
      for (int m = 0; m < 16; m++) {
        float4 xm = xr4[qbase + m];  // uniform address -> scalar load
        acc[m] += xm.x * w4.x + xm.y * w4.y + xm.z * w4.z + xm.w * w4.w;
      }
    }
  }

  // partial store: PP[kc][m][jj0+lane], coalesced 256B per m
  float* pp = ws + WS_PP + (size_t)kc * 16 * 12288 + jj0 + lane;
  #pragma unroll
  for (int m = 0; m < 16; m++) pp[(size_t)m * 12288] = acc[m];
}

// ---------------- Kernel B2: reduce proj partials over kc ----------------
__global__ __launch_bounds__(256) void proj_reduce_kernel(float* __restrict__ ws) {
  int tid = blockIdx.x * 256 + threadIdx.x;  // 0..196607
  int m = tid / 12288;
  int j = tid - m * 12288;
  float acc = 0.f;
  #pragma unroll
  for (int kc = 0; kc < 16; kc++)
    acc += ws[WS_PP + ((size_t)(kc * 16 + m)) * 12288 + j];
  int sel = j >> 12, jj = j & 4095;
  int h = jj >> 7, d = jj & 127;
  ws[WS_Q + sel * 65536 + (h * 16 + m) * 128 + d] = acc;
}

// ---------------- Kernel C1: attention main pass (unchanged from round 3) ----------------
__global__ __launch_bounds__(256) void attn_kernel(const float* __restrict__ cacheK,
                                                   const float* __restrict__ cacheV,
                                                   const float* __restrict__ noise,
                                                   const float* __restrict__ taup,
                                                   float* __restrict__ ws) {
  __shared__ float red[4 * 2048];      // 32KB, rotation-swizzled [wave][lane][32]
  __shared__ float sred[2][4][16];
  int h = blockIdx.x >> 5, b = blockIdx.x & 31;
  int widx = threadIdx.x >> 6, lane = threadIdx.x & 63;
  int m8 = lane & 7, sl = lane >> 3;
  int rsel = lane >> 4;        // row slot this lane handles for e2/s-sums
  int msel = lane & 15;        // m this lane handles for e2/s-sums
  int tsel = (lane >> 3) & 1;  // which t-half holds msel
  float inv_tau = 1.0f / taup[0];

  float qv[2][16];
  #pragma unroll
  for (int t = 0; t < 2; t++) {
    const float4* qp = (const float4*)(ws + WS_Q + ((size_t)(h * 16) + m8 + 8 * t) * 128 + sl * 16);
    #pragma unroll
    for (int jq = 0; jq < 4; jq++) {
      float4 v = qp[jq];
      qv[t][jq * 4] = v.x; qv[t][jq * 4 + 1] = v.y;
      qv[t][jq * 4 + 2] = v.z; qv[t][jq * 4 + 3] = v.w;
    }
  }
  float oacc[2][16];
  #pragma unroll
  for (int t = 0; t < 2; t++)
    #pragma unroll
    for (int j = 0; j < 16; j++) oacc[t][j] = 0.f;
  float s1 = 0.f, s2 = 0.f;

  const float* nbase = noise + ((size_t)h * 16 + msel) * PM_;
  float* e2base = ws + WS_E2 + (size_t)h * PM_ * 16 + msel;
  const float* kc_base = cacheK + (size_t)h * P_ * D_;
  const float* vc_base = cacheV + (size_t)h * P_ * D_;
  const float* kn_base = ws + WS_K + (size_t)h * 16 * 128;
  const float* vn_base = ws + WS_V + (size_t)h * 16 * 128;

  int g0 = b * 64;
  int gN = (b == 31) ? 68 : 64;
  for (int gl = widx; gl < gN; gl += 4) {
    int p0 = (g0 + gl) * 4;
    const float *kb, *vb;
    if (p0 < P_) { kb = kc_base + (size_t)p0 * D_; vb = vc_base + (size_t)p0 * D_; }
    else { kb = kn_base + (size_t)(p0 - P_) * D_; vb = vn_base + (size_t)(p0 - P_) * D_; }

    float pr[4][2];
    #pragma unroll
    for (int r = 0; r < 4; r++) {
      float4 kq[4];
      const float4* krp = (const float4*)(kb + r * D_ + sl * 16);
      kq[0] = krp[0]; kq[1] = krp[1]; kq[2] = krp[2]; kq[3] = krp[3];
      const float* kk = (const float*)kq;
      float t0 = 0.f, t1 = 0.f;
      #pragma unroll
      for (int j = 0; j < 16; j++) { t0 += kk[j] * qv[0][j]; t1 += kk[j] * qv[1][j]; }
      pr[r][0] = t0; pr[r][1] = t1;
    }
    float cc[4][2];
    #pragma unroll
    for (int r = 0; r < 4; r++)
      #pragma unroll
      for (int t = 0; t < 2; t++) {
        float v = pr[r][t];
        v += __shfl_xor(v, 8, 64);
        v += __shfl_xor(v, 16, 64);
        v += __shfl_xor(v, 32, 64);
        cc[r][t] = v;
      }

    float nz = nbase[p0 + rsel];
    float myc = cc[rsel][tsel];
    float e2 = __expf((myc + nz) * inv_tau);
    e2base[(size_t)(p0 + rsel) * 16] = e2;
    s2 += e2;

    float e1[4][2];
    #pragma unroll
    for (int r = 0; r < 4; r++) {
      e1[r][0] = __expf(cc[r][0]);
      e1[r][1] = __expf(cc[r][1]);
    }
    s1 += e1[rsel][tsel];

    #pragma unroll
    for (int r = 0; r < 4; r++) {
      float4 vq[4];
      const float4* vrp = (const float4*)(vb + r * D_ + sl * 16);
      vq[0] = vrp[0]; vq[1] = vrp[1]; vq[2] = vrp[2]; vq[3] = vrp[3];
      const float* vv = (const float*)vq;
      float ea = e1[r][0], eb = e1[r][1];
      #pragma unroll
      for (int j = 0; j < 16; j++) {
        oacc[0][j] += ea * vv[j];
        oacc[1][j] += eb * vv[j];
      }
    }
  }

  s1 += __shfl_xor(s1, 16, 64); s1 += __shfl_xor(s1, 32, 64);
  s2 += __shfl_xor(s2, 16, 64); s2 += __shfl_xor(s2, 32, 64);
  if (lane < 16) { sred[0][widx][lane] = s1; sred[1][widx][lane] = s2; }

  float* rw = red + widx * 2048 + lane * 32;
  #pragma unroll
  for (int t = 0; t < 2; t++)
    #pragma unroll
    for (int j = 0; j < 16; j++) {
      int i = t * 16 + j;
      rw[(i + lane) & 31] = oacc[t][j];
    }
  __syncthreads();

  float* po = ws + WS_PO + (size_t)(h * 32 + b) * 2048;
  for (int e = threadIdx.x; e < 2048; e += 256) {
    int ln = e >> 5, i = e & 31;
    int phys = (ln << 5) + ((i + ln) & 31);
    float v = red[phys] + red[phys + 2048] + red[phys + 4096] + red[phys + 6144];
    int mo = (ln & 7) + 8 * (i >> 4);
    int d = (ln >> 3) * 16 + (i & 15);
    po[mo * 128 + d] = v;
  }
  if (threadIdx.x < 16) {
    int mm = threadIdx.x;
    float a  = sred[0][0][mm] + sred[0][1][mm] + sred[0][2][mm] + sred[0][3][mm];
    float c2 = sred[1][0][mm] + sred[1][1][mm] + sred[1][2][mm] + sred[1][3][mm];
    ws[WS_SP1 + (size_t)(h * 32 + b) * 16 + mm] = a;
    ws[WS_SP2 + (size_t)(h * 32 + b) * 16 + mm] = c2;
  }
}

// ---------------- Kernel S: final s1/s2 sums + 1/s2 ----------------
__global__ __launch_bounds__(256) void sums_kernel(float* __restrict__ ws) {
  int tid = blockIdx.x * 256 + threadIdx.x;
  if (tid >= 512) return;
  int h = tid >> 4, m = tid & 15;
  float a = 0.f, c2 = 0.f;
  #pragma unroll
  for (int b = 0; b < 32; b++) {
    a  += ws[WS_SP1 + (size_t)(h * 32 + b) * 16 + m];
    c2 += ws[WS_SP2 + (size_t)(h * 32 + b) * 16 + m];
  }
  ws[WS_S1 + tid] = a;
  ws[WS_S2 + tid] = c2;
  ws[WS_IS2 + tid] = 1.0f / c2;
}

// ---------------- Kernel D: o2 epilogue ----------------
__global__ __launch_bounds__(256) void epilogue_kernel(const float* __restrict__ ws,
                                                       float* __restrict__ out) {
  int tid = blockIdx.x * 256 + threadIdx.x;  // 0..65535
  int mm = tid >> 12, j = tid & 4095;
  int h = j >> 7, d = j & 127;
  float acc = 0.f;
  #pragma unroll
  for (int b = 0; b < 32; b++)
    acc += ws[WS_PO + (size_t)(h * 32 + b) * 2048 + mm * 128 + d];
  out[tid] = acc / ws[WS_S1 + h * 16 + mm];
}

// ---------------- Kernel C2: c_out (contiguous e2t reads) ----------------
__global__ __launch_bounds__(256) void cout_kernel(const float* __restrict__ ws,
                                                   float* __restrict__ out) {
  int tid = blockIdx.x * 256 + threadIdx.x;
  if (tid >= H_ * PM_) return;
  int h = tid / PM_, p = tid - h * PM_;
  const float4* e2p = (const float4*)(ws + WS_E2 + ((size_t)h * PM_ + p) * 16);
  const float* is2 = ws + WS_IS2 + h * 16;
  float acc = 0.f;
  #pragma unroll
  for (int q = 0; q < 4; q++) {
    float4 v = e2p[q];
    acc += v.x * is2[q * 4] + v.y * is2[q * 4 + 1] + v.z * is2[q * 4 + 2] + v.w * is2[q * 4 + 3];
  }
  out[65536 + tid] = acc;
}

extern "C" void kernel_launch(void* const* d_in, const int* in_sizes, int n_in,
                              void* d_out, int out_size, void* d_ws, size_t ws_size,
                              hipStream_t stream) {
  const float* X     = (const float*)d_in[0];
  const float* Wq    = (const float*)d_in[1];
  const float* Wk    = (const float*)d_in[2];
  const float* Wv    = (const float*)d_in[3];
  const float* cK    = (const float*)d_in[4];
  const float* cV    = (const float*)d_in[5];
  const float* tau   = (const float*)d_in[6];
  const float* noise = (const float*)d_in[7];
  float* out = (float*)d_out;
  float* ws  = (float*)d_ws;

  rmsnorm_kernel<<<16, 256, 0, stream>>>(X, ws);
  proj_kernel<<<768, 256, 0, stream>>>(Wq, Wk, Wv, ws + WS_XQ, ws);
  proj_reduce_kernel<<<768, 256, 0, stream>>>(ws);
  attn_kernel<<<1024, 256, 0, stream>>>(cK, cV, noise, tau, ws);
  sums_kernel<<<2, 256, 0, stream>>>(ws);
  epilogue_kernel<<<256, 256, 0, stream>>>(ws, out);
  cout_kernel<<<1026, 256, 0, stream>>>(ws, out);
}

// Round 5
// 215.454 us; speedup vs baseline: 4.1293x; 1.4627x over previous
//
#include <hip/hip_runtime.h>

#define M_ 16
#define H_ 32
#define D_ 128
#define P_ 8192
#define N_ 4096
#define PM_ 8208   // P + M

// workspace layout (float offsets) — no region needs pre-zeroing
#define WS_Q    0          // [32][16][128] q
#define WS_K    65536      // [32][16][128] new k
#define WS_V    131072     // [32][16][128] new v
#define WS_S1   196608     // [512] final denominators (exp(c))
#define WS_S2   197120     // [512] final denominators (perturbed)
#define WS_IS2  197632     // [512] 1/s2
#define WS_XQ   198144     // x_norm as float4 [1024][16] (n-quad major, m minor)
#define WS_E2   263680     // e2t [32][8208][16]  (h, p, m) — transposed for coalescing
#define WS_PP   263680     // proj partials [16][16][12288] — ALIASES E2 (consumed before attn)
#define WS_PO   4466176    // attn O partials [32][32][16][128] (h, block, m, d)
#define WS_SP1  6563328    // [32*32*16] s1 partials per (h, block, m)
#define WS_SP2  6579712    // [32*32*16]
// total = 6,596,096 floats = 26.4 MB

typedef __attribute__((address_space(1))) const void gvoid_t;
typedef __attribute__((address_space(3))) void lvoid_t;

// ---------------- Kernel A: RMS norm, write transposed-quad layout ----------------
__global__ __launch_bounds__(256) void rmsnorm_kernel(const float* __restrict__ X,
                                                      float* __restrict__ ws) {
  int m = blockIdx.x, t = threadIdx.x;
  __shared__ float red[256];
  const float4* X4 = (const float4*)(X + (size_t)m * N_);
  float s = 0.f;
  #pragma unroll
  for (int q = 0; q < 4; q++) {
    float4 v = X4[t + q * 256];
    s += v.x * v.x + v.y * v.y + v.z * v.z + v.w * v.w;
  }
  red[t] = s;
  __syncthreads();
  for (int off = 128; off > 0; off >>= 1) {
    if (t < off) red[t] += red[t + off];
    __syncthreads();
  }
  float scale = rsqrtf(red[0] * (1.0f / N_));
  float4* xq = (float4*)(ws + WS_XQ);
  #pragma unroll
  for (int q = 0; q < 4; q++) {
    int nq = t + q * 256;
    float4 v = X4[nq];
    v.x *= scale; v.y *= scale; v.z *= scale; v.w *= scale;
    xq[nq * 16 + m] = v;  // xq[n/4][m]
  }
}

// ---------------- Kernel B: QKV projection ----------------
// kc is BLOCK-uniform (scalar): x loads provably uniform -> s_load path.
// W staged via global_load_lds (16B) with source-swizzled global addresses,
// linear LDS dest, XOR-swizzled ds_read_b128 (involution: cq = c8 ^ g8).
// Per-wave private 8KB tile, no barriers. j-per-lane accumulation, acc[16].
__global__ __launch_bounds__(256, 4) void proj_kernel(const float* __restrict__ Wq,
                                                      const float* __restrict__ Wk,
                                                      const float* __restrict__ Wv,
                                                      const float* __restrict__ xr,
                                                      float* __restrict__ ws) {
  __shared__ float tile[4 * 2048];  // 8KB per wave
  int widx = threadIdx.x >> 6, lane = threadIdx.x & 63;
  int kc = blockIdx.x / 48;                 // 0..15, scalar (blockIdx only)
  int jt = (blockIdx.x % 48) * 4 + widx;    // 0..191
  int jj0 = jt * 64;
  int sel = jj0 >> 12;                      // 0=q 1=k 2=v
  int j0 = jj0 & 4095;
  const float* Wm = (sel == 0) ? Wq : ((sel == 1) ? Wk : Wv);
  int n0 = kc * 256;

  float* tl = tile + widx * 2048;
  int g8 = lane >> 3;        // row-subgroup 0..7
  int c8 = lane & 7;         // col-slot 0..7
  int cq = c8 ^ g8;          // source-swizzled col-quad (involution)

  const float* gsrc[8];
  #pragma unroll
  for (int i = 0; i < 8; i++)
    gsrc[i] = Wm + (size_t)(j0 + i * 8 + g8) * N_ + n0 + cq * 4;

  const float4* tl4 = (const float4*)tl;
  int rbase = lane * 8;      // float4-index base of this lane's j-row
  int swz = lane & 7;

  const float4* xr4 = (const float4*)xr;
  float acc[16];
  #pragma unroll
  for (int m = 0; m < 16; m++) acc[m] = 0.f;

  for (int ti = 0; ti < 8; ti++) {
    #pragma unroll
    for (int i = 0; i < 8; i++)
      __builtin_amdgcn_global_load_lds((gvoid_t*)(gsrc[i] + ti * 32),
                                       (lvoid_t*)(tl + i * 256), 16, 0, 0);
    asm volatile("s_waitcnt vmcnt(0)" ::: "memory");
    __builtin_amdgcn_sched_barrier(0);

    int nqb = (n0 >> 2) + ti * 8;
    #pragma unroll
    for (int k = 0; k < 8; k++) {
      float4 w4 = tl4[rbase + (k ^ swz)];   // swizzled read: banks spread
      int qbase = (nqb + k) * 16;
      #pragma unroll
      for (int m = 0; m < 16; m++) {
        float4 xm = xr4[qbase + m];  // uniform address -> scalar load
        acc[m] += xm.x * w4.x + xm.y * w4.y + xm.z * w4.z + xm.w * w4.w;
      }
    }
  }

  float* pp = ws + WS_PP + (size_t)kc * 16 * 12288 + jj0 + lane;
  #pragma unroll
  for (int m = 0; m < 16; m++) pp[(size_t)m * 12288] = acc[m];
}

// ---------------- Kernel B2: reduce proj partials over kc ----------------
__global__ __launch_bounds__(256) void proj_reduce_kernel(float* __restrict__ ws) {
  int tid = blockIdx.x * 256 + threadIdx.x;  // 0..196607
  int m = tid / 12288;
  int j = tid - m * 12288;
  float acc = 0.f;
  #pragma unroll
  for (int kc = 0; kc < 16; kc++)
    acc += ws[WS_PP + ((size_t)(kc * 16 + m)) * 12288 + j];
  int sel = j >> 12, jj = j & 4095;
  int h = jj >> 7, d = jj & 127;
  ws[WS_Q + sel * 65536 + (h * 16 + m) * 128 + d] = acc;
}

// ---------------- Kernel C1: attention main pass ----------------
// Round-5 fix: NO runtime-indexed locals (cc/e1 selected via cndmask trees on
// lane bits) -> no scratch. nz load hoisted to iteration top.
__global__ __launch_bounds__(256) void attn_kernel(const float* __restrict__ cacheK,
                                                   const float* __restrict__ cacheV,
                                                   const float* __restrict__ noise,
                                                   const float* __restrict__ taup,
                                                   float* __restrict__ ws) {
  __shared__ float red[4 * 2048];      // 32KB, rotation-swizzled [wave][lane][32]
  __shared__ float sred[2][4][16];
  int h = blockIdx.x >> 5, b = blockIdx.x & 31;
  int widx = threadIdx.x >> 6, lane = threadIdx.x & 63;
  int m8 = lane & 7, sl = lane >> 3;
  int rsel = lane >> 4;        // row slot this lane handles for e2/s-sums
  int msel = lane & 15;        // m this lane handles for e2/s-sums
  bool tb = (lane >> 3) & 1;   // which t-half holds msel
  bool rb0 = rsel & 1, rb1 = (rsel >> 1) & 1;
  float inv_tau = 1.0f / taup[0];

  float qv[2][16];
  #pragma unroll
  for (int t = 0; t < 2; t++) {
    const float4* qp = (const float4*)(ws + WS_Q + ((size_t)(h * 16) + m8 + 8 * t) * 128 + sl * 16);
    #pragma unroll
    for (int jq = 0; jq < 4; jq++) {
      float4 v = qp[jq];
      qv[t][jq * 4] = v.x; qv[t][jq * 4 + 1] = v.y;
      qv[t][jq * 4 + 2] = v.z; qv[t][jq * 4 + 3] = v.w;
    }
  }
  float oacc[2][16];
  #pragma unroll
  for (int t = 0; t < 2; t++)
    #pragma unroll
    for (int j = 0; j < 16; j++) oacc[t][j] = 0.f;
  float s1 = 0.f, s2 = 0.f;

  const float* nbase = noise + ((size_t)h * 16 + msel) * PM_;
  float* e2base = ws + WS_E2 + (size_t)h * PM_ * 16 + msel;
  const float* kc_base = cacheK + (size_t)h * P_ * D_;
  const float* vc_base = cacheV + (size_t)h * P_ * D_;
  const float* kn_base = ws + WS_K + (size_t)h * 16 * 128;
  const float* vn_base = ws + WS_V + (size_t)h * 16 * 128;

  int g0 = b * 64;
  int gN = (b == 31) ? 68 : 64;
  for (int gl = widx; gl < gN; gl += 4) {
    int p0 = (g0 + gl) * 4;
    const float *kb, *vb;
    if (p0 < P_) { kb = kc_base + (size_t)p0 * D_; vb = vc_base + (size_t)p0 * D_; }
    else { kb = kn_base + (size_t)(p0 - P_) * D_; vb = vn_base + (size_t)(p0 - P_) * D_; }

    float nz = nbase[p0 + rsel];   // issued early; latency hides under dots

    float pr[4][2];
    #pragma unroll
    for (int r = 0; r < 4; r++) {
      float4 kq[4];
      const float4* krp = (const float4*)(kb + r * D_ + sl * 16);
      kq[0] = krp[0]; kq[1] = krp[1]; kq[2] = krp[2]; kq[3] = krp[3];
      const float* kk = (const float*)kq;
      float t0 = 0.f, t1 = 0.f;
      #pragma unroll
      for (int j = 0; j < 16; j++) { t0 += kk[j] * qv[0][j]; t1 += kk[j] * qv[1][j]; }
      pr[r][0] = t0; pr[r][1] = t1;
    }
    float cc[4][2];
    #pragma unroll
    for (int r = 0; r < 4; r++)
      #pragma unroll
      for (int t = 0; t < 2; t++) {
        float v = pr[r][t];
        v += __shfl_xor(v, 8, 64);
        v += __shfl_xor(v, 16, 64);
        v += __shfl_xor(v, 32, 64);
        cc[r][t] = v;
      }

    // static select tree (7 cndmask) — NO runtime array indexing
    float a0 = tb ? cc[0][1] : cc[0][0];
    float a1 = tb ? cc[1][1] : cc[1][0];
    float a2 = tb ? cc[2][1] : cc[2][0];
    float a3 = tb ? cc[3][1] : cc[3][0];
    float b0 = rb0 ? a1 : a0;
    float b1 = rb0 ? a3 : a2;
    float myc = rb1 ? b1 : b0;

    float e2 = __expf((myc + nz) * inv_tau);
    e2base[(size_t)(p0 + rsel) * 16] = e2;
    s2 += e2;

    float e1[4][2];
    #pragma unroll
    for (int r = 0; r < 4; r++) {
      e1[r][0] = __expf(cc[r][0]);
      e1[r][1] = __expf(cc[r][1]);
    }
    float f0 = tb ? e1[0][1] : e1[0][0];
    float f1 = tb ? e1[1][1] : e1[1][0];
    float f2 = tb ? e1[2][1] : e1[2][0];
    float f3 = tb ? e1[3][1] : e1[3][0];
    float g0s = rb0 ? f1 : f0;
    float g1s = rb0 ? f3 : f2;
    s1 += rb1 ? g1s : g0s;

    #pragma unroll
    for (int r = 0; r < 4; r++) {
      float4 vq[4];
      const float4* vrp = (const float4*)(vb + r * D_ + sl * 16);
      vq[0] = vrp[0]; vq[1] = vrp[1]; vq[2] = vrp[2]; vq[3] = vrp[3];
      const float* vv = (const float*)vq;
      float ea = e1[r][0], eb = e1[r][1];
      #pragma unroll
      for (int j = 0; j < 16; j++) {
        oacc[0][j] += ea * vv[j];
        oacc[1][j] += eb * vv[j];
      }
    }
  }

  s1 += __shfl_xor(s1, 16, 64); s1 += __shfl_xor(s1, 32, 64);
  s2 += __shfl_xor(s2, 16, 64); s2 += __shfl_xor(s2, 32, 64);
  if (lane < 16) { sred[0][widx][lane] = s1; sred[1][widx][lane] = s2; }

  float* rw = red + widx * 2048 + lane * 32;
  #pragma unroll
  for (int t = 0; t < 2; t++)
    #pragma unroll
    for (int j = 0; j < 16; j++) {
      int i = t * 16 + j;
      rw[(i + lane) & 31] = oacc[t][j];
    }
  __syncthreads();

  float* po = ws + WS_PO + (size_t)(h * 32 + b) * 2048;
  for (int e = threadIdx.x; e < 2048; e += 256) {
    int ln = e >> 5, i = e & 31;
    int phys = (ln << 5) + ((i + ln) & 31);
    float v = red[phys] + red[phys + 2048] + red[phys + 4096] + red[phys + 6144];
    int mo = (ln & 7) + 8 * (i >> 4);
    int d = (ln >> 3) * 16 + (i & 15);
    po[mo * 128 + d] = v;
  }
  if (threadIdx.x < 16) {
    int mm = threadIdx.x;
    float a  = sred[0][0][mm] + sred[0][1][mm] + sred[0][2][mm] + sred[0][3][mm];
    float c2 = sred[1][0][mm] + sred[1][1][mm] + sred[1][2][mm] + sred[1][3][mm];
    ws[WS_SP1 + (size_t)(h * 32 + b) * 16 + mm] = a;
    ws[WS_SP2 + (size_t)(h * 32 + b) * 16 + mm] = c2;
  }
}

// ---------------- Kernel S: final s1/s2 sums + 1/s2 ----------------
__global__ __launch_bounds__(256) void sums_kernel(float* __restrict__ ws) {
  int tid = blockIdx.x * 256 + threadIdx.x;
  if (tid >= 512) return;
  int h = tid >> 4, m = tid & 15;
  float a = 0.f, c2 = 0.f;
  #pragma unroll
  for (int b = 0; b < 32; b++) {
    a  += ws[WS_SP1 + (size_t)(h * 32 + b) * 16 + m];
    c2 += ws[WS_SP2 + (size_t)(h * 32 + b) * 16 + m];
  }
  ws[WS_S1 + tid] = a;
  ws[WS_S2 + tid] = c2;
  ws[WS_IS2 + tid] = 1.0f / c2;
}

// ---------------- Kernel D: o2 epilogue ----------------
__global__ __launch_bounds__(256) void epilogue_kernel(const float* __restrict__ ws,
                                                       float* __restrict__ out) {
  int tid = blockIdx.x * 256 + threadIdx.x;  // 0..65535
  int mm = tid >> 12, j = tid & 4095;
  int h = j >> 7, d = j & 127;
  float acc = 0.f;
  #pragma unroll
  for (int b = 0; b < 32; b++)
    acc += ws[WS_PO + (size_t)(h * 32 + b) * 2048 + mm * 128 + d];
  out[tid] = acc / ws[WS_S1 + h * 16 + mm];
}

// ---------------- Kernel C2: c_out (contiguous e2t reads) ----------------
__global__ __launch_bounds__(256) void cout_kernel(const float* __restrict__ ws,
                                                   float* __restrict__ out) {
  int tid = blockIdx.x * 256 + threadIdx.x;
  if (tid >= H_ * PM_) return;
  int h = tid / PM_, p = tid - h * PM_;
  const float4* e2p = (const float4*)(ws + WS_E2 + ((size_t)h * PM_ + p) * 16);
  const float* is2 = ws + WS_IS2 + h * 16;
  float acc = 0.f;
  #pragma unroll
  for (int q = 0; q < 4; q++) {
    float4 v = e2p[q];
    acc += v.x * is2[q * 4] + v.y * is2[q * 4 + 1] + v.z * is2[q * 4 + 2] + v.w * is2[q * 4 + 3];
  }
  out[65536 + tid] = acc;
}

extern "C" void kernel_launch(void* const* d_in, const int* in_sizes, int n_in,
                              void* d_out, int out_size, void* d_ws, size_t ws_size,
                              hipStream_t stream) {
  const float* X     = (const float*)d_in[0];
  const float* Wq    = (const float*)d_in[1];
  const float* Wk    = (const float*)d_in[2];
  const float* Wv    = (const float*)d_in[3];
  const float* cK    = (const float*)d_in[4];
  const float* cV    = (const float*)d_in[5];
  const float* tau   = (const float*)d_in[6];
  const float* noise = (const float*)d_in[7];
  float* out = (float*)d_out;
  float* ws  = (float*)d_ws;

  rmsnorm_kernel<<<16, 256, 0, stream>>>(X, ws);
  proj_kernel<<<768, 256, 0, stream>>>(Wq, Wk, Wv, ws + WS_XQ, ws);
  proj_reduce_kernel<<<768, 256, 0, stream>>>(ws);
  attn_kernel<<<1024, 256, 0, stream>>>(cK, cV, noise, tau, ws);
  sums_kernel<<<2, 256, 0, stream>>>(ws);
  epilogue_kernel<<<256, 256, 0, stream>>>(ws, out);
  cout_kernel<<<1026, 256, 0, stream>>>(ws, out);
}